// Round 1
// baseline (1642.401 us; speedup 1.0000x reference)
//
#include <hip/hip_runtime.h>

#define FEAT 64

// One wave (64 lanes) per edge: lane f gathers x[src][f], atomic-adds into agg[dst][f].
__global__ __launch_bounds__(256) void scatter_kernel(
    const float* __restrict__ x, const int* __restrict__ src,
    const int* __restrict__ dst, float* __restrict__ agg,
    float* __restrict__ cnt, int E, int do_cnt)
{
    int e = blockIdx.x * 4 + (threadIdx.x >> 6);
    if (e >= E) return;
    int lane = threadIdx.x & 63;
    int s = src[e];
    int d = dst[e];
    float v = x[(size_t)s * FEAT + lane];
    atomicAdd(&agg[(size_t)d * FEAT + lane], v);
    if (do_cnt && lane == 0) atomicAdd(&cnt[d], 1.0f);
}

// Lane-per-node sage: out_row = relu(mean_row @ w_l + b_l + x_row @ w_r), written IN PLACE into agg.
// Weight indices are wave-uniform -> scalar loads (s_load), co-issued with v_fmac.
__global__ __launch_bounds__(256) void sage_kernel(
    float* agg,                       // [N,64] in: segment sums, out: relu(sage) (in-place, row-private)
    const float* __restrict__ cnt,    // [N]
    const float* __restrict__ xin,    // [N,64] self features
    const float* __restrict__ w_l, const float* __restrict__ b_l,
    const float* __restrict__ w_r, int n)
{
    int i = blockIdx.x * blockDim.x + threadIdx.x;
    if (i >= n) return;
    float inv = 1.0f / fmaxf(cnt[i], 1.0f);
    float m[FEAT], xr[FEAT];
    const float4* av = (const float4*)(agg + (size_t)i * FEAT);
    const float4* xv = (const float4*)(xin + (size_t)i * FEAT);
#pragma unroll
    for (int q = 0; q < FEAT / 4; q++) {
        float4 a = av[q];
        m[4*q+0] = a.x * inv; m[4*q+1] = a.y * inv;
        m[4*q+2] = a.z * inv; m[4*q+3] = a.w * inv;
        float4 x4 = xv[q];
        xr[4*q+0] = x4.x; xr[4*q+1] = x4.y;
        xr[4*q+2] = x4.z; xr[4*q+3] = x4.w;
    }
    float* o = agg + (size_t)i * FEAT;
    for (int j = 0; j < FEAT; j++) {   // j is wave-uniform
        float acc = b_l[j];
#pragma unroll
        for (int k = 0; k < FEAT; k++) acc += m[k] * w_l[k * FEAT + j];
#pragma unroll
        for (int k = 0; k < FEAT; k++) acc += xr[k] * w_r[k * FEAT + j];
        o[j] = fmaxf(acc, 0.0f);
    }
}

// Lane-per-node dense layer: out_row = (relu?)(x_row @ w + b)
__global__ __launch_bounds__(256) void lin_kernel(
    const float* __restrict__ xin, const float* __restrict__ w,
    const float* __restrict__ b, float* __restrict__ out, int n, int do_relu)
{
    int i = blockIdx.x * blockDim.x + threadIdx.x;
    if (i >= n) return;
    float xr[FEAT];
    const float4* xv = (const float4*)(xin + (size_t)i * FEAT);
#pragma unroll
    for (int q = 0; q < FEAT / 4; q++) {
        float4 x4 = xv[q];
        xr[4*q+0] = x4.x; xr[4*q+1] = x4.y;
        xr[4*q+2] = x4.z; xr[4*q+3] = x4.w;
    }
    float* o = out + (size_t)i * FEAT;
    for (int j = 0; j < FEAT; j++) {   // j is wave-uniform
        float acc = b[j];
#pragma unroll
        for (int k = 0; k < FEAT; k++) acc += xr[k] * w[k * FEAT + j];
        o[j] = do_relu ? fmaxf(acc, 0.0f) : acc;
    }
}

extern "C" void kernel_launch(void* const* d_in, const int* in_sizes, int n_in,
                              void* d_out, int out_size, void* d_ws, size_t ws_size,
                              hipStream_t stream) {
    const float* h      = (const float*)d_in[0];
    const int*   ei     = (const int*)d_in[1];
    const float* w1_l   = (const float*)d_in[2];
    const float* b1_l   = (const float*)d_in[3];
    const float* w1_r   = (const float*)d_in[4];
    const float* w_lin1 = (const float*)d_in[5];
    const float* b_lin1 = (const float*)d_in[6];
    const float* w2_l   = (const float*)d_in[7];
    const float* b2_l   = (const float*)d_in[8];
    const float* w2_r   = (const float*)d_in[9];
    const float* w_lin2 = (const float*)d_in[10];
    const float* b_lin2 = (const float*)d_in[11];

    const int N = in_sizes[0] / FEAT;
    const int E = in_sizes[1] / 2;
    const int* src  = ei;
    const int* dst_ = ei + E;

    // Workspace layout: agg[N*64] | cnt[N] | x2[N*64]  (~52 MB)
    float* agg = (float*)d_ws;
    float* cnt = agg + (size_t)N * FEAT;
    float* x2  = cnt + N;

    const int sblk = (E + 3) / 4;
    const int nblk = (N + 255) / 256;

    // ---- Layer 1: conv1 + lin1 ----
    hipMemsetAsync(agg, 0, ((size_t)N * FEAT + N) * sizeof(float), stream); // agg + cnt
    scatter_kernel<<<sblk, 256, 0, stream>>>(h, src, dst_, agg, cnt, E, 1);
    sage_kernel<<<nblk, 256, 0, stream>>>(agg, cnt, h, w1_l, b1_l, w1_r, N);
    lin_kernel<<<nblk, 256, 0, stream>>>(agg, w_lin1, b_lin1, x2, N, 1);

    // ---- Layer 2: conv2 + lin2 (cnt reused) ----
    hipMemsetAsync(agg, 0, (size_t)N * FEAT * sizeof(float), stream);
    scatter_kernel<<<sblk, 256, 0, stream>>>(x2, src, dst_, agg, cnt, E, 0);
    sage_kernel<<<nblk, 256, 0, stream>>>(agg, cnt, x2, w2_l, b2_l, w2_r, N);
    lin_kernel<<<nblk, 256, 0, stream>>>(agg, w_lin2, b_lin2, (float*)d_out, N, 0);
}

// Round 2
// 644.104 us; speedup vs baseline: 2.5499x; 2.5499x over previous
//
#include <hip/hip_runtime.h>

#define FEAT 64

// ---------------- CSR build ----------------

__global__ __launch_bounds__(256) void hist_kernel(
    const int* __restrict__ dst, int* __restrict__ deg, int E)
{
    int e = blockIdx.x * 256 + threadIdx.x;
    if (e < E) atomicAdd(&deg[dst[e]], 1);
}

// Per-block inclusive scan (Hillis-Steele) -> exclusive prefix + block sums.
__global__ __launch_bounds__(256) void scan_local_kernel(
    const int* __restrict__ deg, int* __restrict__ excl,
    int* __restrict__ bsum, int N)
{
    __shared__ int s[256];
    int i = blockIdx.x * 256 + threadIdx.x;
    int v = (i < N) ? deg[i] : 0;
    s[threadIdx.x] = v;
    __syncthreads();
    for (int off = 1; off < 256; off <<= 1) {
        int t = (threadIdx.x >= (unsigned)off) ? s[threadIdx.x - off] : 0;
        __syncthreads();
        s[threadIdx.x] += t;
        __syncthreads();
    }
    if (i < N) excl[i] = s[threadIdx.x] - v;
    if (threadIdx.x == 255) bsum[blockIdx.x] = s[255];
}

// Single-block scan of the block sums (NB <= 512).
__global__ __launch_bounds__(512) void scan_blocks_kernel(
    int* __restrict__ bsum, int NB)
{
    __shared__ int s[512];
    int v = (threadIdx.x < (unsigned)NB) ? bsum[threadIdx.x] : 0;
    s[threadIdx.x] = v;
    __syncthreads();
    for (int off = 1; off < 512; off <<= 1) {
        int t = (threadIdx.x >= (unsigned)off) ? s[threadIdx.x - off] : 0;
        __syncthreads();
        s[threadIdx.x] += t;
        __syncthreads();
    }
    if (threadIdx.x < (unsigned)NB) bsum[threadIdx.x] = s[threadIdx.x] - v; // exclusive
}

__global__ __launch_bounds__(256) void finalize_kernel(
    const int* __restrict__ excl, const int* __restrict__ boff,
    int* __restrict__ rowptr, int* __restrict__ cursor, int N, int E)
{
    int i = blockIdx.x * 256 + threadIdx.x;
    if (i < N) {
        int r = excl[i] + boff[i >> 8];
        rowptr[i] = r;
        cursor[i] = r;
    }
    if (i == 0) rowptr[N] = E;
}

__global__ __launch_bounds__(256) void fill_kernel(
    const int* __restrict__ src, const int* __restrict__ dst,
    int* __restrict__ cursor, int* __restrict__ csr_src, int E)
{
    int e = blockIdx.x * 256 + threadIdx.x;
    if (e < E) {
        int d = dst[e];
        int p = atomicAdd(&cursor[d], 1);
        csr_src[p] = src[e];
    }
}

// ---------------- Aggregation: gather-mean, wave per node ----------------
// lane f accumulates x[neighbor][f]; row reads are 256 B coalesced.
__global__ __launch_bounds__(256) void gather_kernel(
    const float* __restrict__ x, const int* __restrict__ rowptr,
    const int* __restrict__ csr_src, float* __restrict__ mean, int N)
{
    int node = blockIdx.x * 4 + (threadIdx.x >> 6);
    node = __builtin_amdgcn_readfirstlane(node);   // wave-uniform -> scalar control
    if (node >= N) return;
    int lane = threadIdx.x & 63;
    int beg = rowptr[node], end = rowptr[node + 1];
    float acc = 0.0f;
    int e = beg;
    for (; e + 1 < end; e += 2) {                  // unroll 2 for ILP
        int s0 = csr_src[e], s1 = csr_src[e + 1];
        float v0 = x[(size_t)s0 * FEAT + lane];
        float v1 = x[(size_t)s1 * FEAT + lane];
        acc += v0; acc += v1;
    }
    if (e < end) acc += x[(size_t)csr_src[e] * FEAT + lane];
    float inv = 1.0f / fmaxf((float)(end - beg), 1.0f);
    mean[(size_t)node * FEAT + lane] = acc * inv;
}

// ---------------- Node transforms (lane-per-node, scalar weight loads) ----------------

// out_row = relu(mean_row @ w_l + b_l + x_row @ w_r), written IN PLACE into mean.
__global__ __launch_bounds__(256) void sage_kernel(
    float* mean,                      // [N,64] in: mean rows, out: relu(sage)
    const float* __restrict__ xin,    // [N,64]
    const float* __restrict__ w_l, const float* __restrict__ b_l,
    const float* __restrict__ w_r, int n)
{
    int i = blockIdx.x * blockDim.x + threadIdx.x;
    if (i >= n) return;
    float m[FEAT], xr[FEAT];
    const float4* mv = (const float4*)(mean + (size_t)i * FEAT);
    const float4* xv = (const float4*)(xin + (size_t)i * FEAT);
#pragma unroll
    for (int q = 0; q < FEAT / 4; q++) {
        float4 a = mv[q];
        m[4*q+0] = a.x; m[4*q+1] = a.y; m[4*q+2] = a.z; m[4*q+3] = a.w;
        float4 b = xv[q];
        xr[4*q+0] = b.x; xr[4*q+1] = b.y; xr[4*q+2] = b.z; xr[4*q+3] = b.w;
    }
    float* o = mean + (size_t)i * FEAT;
    for (int j0 = 0; j0 < FEAT; j0 += 4) {
        int j = __builtin_amdgcn_readfirstlane(j0);  // provably uniform -> s_load weights
        float a0 = b_l[j+0], a1 = b_l[j+1], a2 = b_l[j+2], a3 = b_l[j+3];
#pragma unroll
        for (int k = 0; k < FEAT; k++) {
            float mk = m[k], xk = xr[k];
            const float* wl = w_l + k * FEAT + j;
            const float* wr = w_r + k * FEAT + j;
            a0 += mk * wl[0]; a1 += mk * wl[1]; a2 += mk * wl[2]; a3 += mk * wl[3];
            a0 += xk * wr[0]; a1 += xk * wr[1]; a2 += xk * wr[2]; a3 += xk * wr[3];
        }
        float4 st = make_float4(fmaxf(a0, 0.0f), fmaxf(a1, 0.0f),
                                fmaxf(a2, 0.0f), fmaxf(a3, 0.0f));
        *(float4*)(o + j) = st;
    }
}

// out_row = (relu?)(x_row @ w + b)
__global__ __launch_bounds__(256) void lin_kernel(
    const float* __restrict__ xin, const float* __restrict__ w,
    const float* __restrict__ b, float* __restrict__ out, int n, int do_relu)
{
    int i = blockIdx.x * blockDim.x + threadIdx.x;
    if (i >= n) return;
    float xr[FEAT];
    const float4* xv = (const float4*)(xin + (size_t)i * FEAT);
#pragma unroll
    for (int q = 0; q < FEAT / 4; q++) {
        float4 a = xv[q];
        xr[4*q+0] = a.x; xr[4*q+1] = a.y; xr[4*q+2] = a.z; xr[4*q+3] = a.w;
    }
    float* o = out + (size_t)i * FEAT;
    for (int j0 = 0; j0 < FEAT; j0 += 4) {
        int j = __builtin_amdgcn_readfirstlane(j0);
        float a0 = b[j+0], a1 = b[j+1], a2 = b[j+2], a3 = b[j+3];
#pragma unroll
        for (int k = 0; k < FEAT; k++) {
            float xk = xr[k];
            const float* wp = w + k * FEAT + j;
            a0 += xk * wp[0]; a1 += xk * wp[1]; a2 += xk * wp[2]; a3 += xk * wp[3];
        }
        float4 st;
        if (do_relu)
            st = make_float4(fmaxf(a0, 0.0f), fmaxf(a1, 0.0f),
                             fmaxf(a2, 0.0f), fmaxf(a3, 0.0f));
        else
            st = make_float4(a0, a1, a2, a3);
        *(float4*)(o + j) = st;
    }
}

extern "C" void kernel_launch(void* const* d_in, const int* in_sizes, int n_in,
                              void* d_out, int out_size, void* d_ws, size_t ws_size,
                              hipStream_t stream) {
    const float* h      = (const float*)d_in[0];
    const int*   ei     = (const int*)d_in[1];
    const float* w1_l   = (const float*)d_in[2];
    const float* b1_l   = (const float*)d_in[3];
    const float* w1_r   = (const float*)d_in[4];
    const float* w_lin1 = (const float*)d_in[5];
    const float* b_lin1 = (const float*)d_in[6];
    const float* w2_l   = (const float*)d_in[7];
    const float* b2_l   = (const float*)d_in[8];
    const float* w2_r   = (const float*)d_in[9];
    const float* w_lin2 = (const float*)d_in[10];
    const float* b_lin2 = (const float*)d_in[11];

    const int N = in_sizes[0] / FEAT;
    const int E = in_sizes[1] / 2;
    const int* src  = ei;
    const int* dst_ = ei + E;

    const int NB = (N + 255) / 256;        // 391 for N=100000 (<= 512)

    // Workspace layout:
    // deg/cursor[N] | excl[N] | bsum[512] | rowptr[N+1] | csr_src[E] | mean[N*64] | x2[N*64]
    int*   deg     = (int*)d_ws;
    int*   excl    = deg + N;
    int*   bsum    = excl + N;
    int*   rowptr  = bsum + 512;
    int*   csr_src = rowptr + (N + 1);
    float* mean    = (float*)(csr_src + E);
    float* x2      = mean + (size_t)N * FEAT;

    const int eblk = (E + 255) / 256;
    const int nblk = NB;
    const int gblk = (N + 3) / 4;

    // ---- CSR build (once, reused by both conv layers) ----
    hipMemsetAsync(deg, 0, (size_t)N * sizeof(int), stream);
    hist_kernel<<<eblk, 256, 0, stream>>>(dst_, deg, E);
    scan_local_kernel<<<nblk, 256, 0, stream>>>(deg, excl, bsum, N);
    scan_blocks_kernel<<<1, 512, 0, stream>>>(bsum, NB);
    finalize_kernel<<<nblk, 256, 0, stream>>>(excl, bsum, rowptr, deg /*cursor*/, N, E);
    fill_kernel<<<eblk, 256, 0, stream>>>(src, dst_, deg /*cursor*/, csr_src, E);

    // ---- Layer 1: conv1 + lin1 ----
    gather_kernel<<<gblk, 256, 0, stream>>>(h, rowptr, csr_src, mean, N);
    sage_kernel<<<nblk, 256, 0, stream>>>(mean, h, w1_l, b1_l, w1_r, N);
    lin_kernel<<<nblk, 256, 0, stream>>>(mean, w_lin1, b_lin1, x2, N, 1);

    // ---- Layer 2: conv2 + lin2 ----
    gather_kernel<<<gblk, 256, 0, stream>>>(x2, rowptr, csr_src, mean, N);
    sage_kernel<<<nblk, 256, 0, stream>>>(mean, x2, w2_l, b2_l, w2_r, N);
    lin_kernel<<<nblk, 256, 0, stream>>>(mean, w_lin2, b_lin2, (float*)d_out, N, 0);
}